// Round 13
// baseline (48.122 us; speedup 1.0000x reference)
//
#include <hip/hip_runtime.h>

typedef _Float16 h2   __attribute__((ext_vector_type(2)));
typedef __fp16   f16x8 __attribute__((ext_vector_type(8)));
typedef float    f32x4 __attribute__((ext_vector_type(4)));

#define IH 512
#define IW 512
#define OH 502
#define OW 502
#define NIMG 48
#define ROWS 32
#define NSTRIP 16                 // 16*32 = 512 >= 502
#define NBLK (NSTRIP * NIMG)      // 768
#define RPAD 268                  // h2 words per (row,q) line; stride 1072B -> bank spread
#define LASTS 20                  // pair-steps S = 0..20 (42 input rows)
#define C1V 1.0e-4f
#define C2V 9.0e-4f

// gaussian(win=11, sigma=1.5), normalized
constexpr float GFc[11] = {
    0.00102838f, 0.00759876f, 0.03600078f, 0.10936070f, 0.21300554f,
    0.26601173f, 0.21300554f, 0.10936070f, 0.03600078f, 0.00759876f,
    0.00102838f};

static __device__ __forceinline__ h2 pkrtz(float a, float b) {
    return __builtin_bit_cast(h2, __builtin_amdgcn_cvt_pkrtz(a, b));
}

// packed-f16 constant into SGPR (VOP3P has no packed literals)
static __device__ __forceinline__ h2 sgpr_h2(float a, float b) {
    h2 v = h2{(_Float16)a, (_Float16)b};
    int i = __builtin_amdgcn_readfirstlane(__builtin_bit_cast(int, v));
    return __builtin_bit_cast(h2, i);
}

struct Pre {  // pipelined loads for one pair-step
    float a2, a3;   // yt col c,   rows 2X+1, 2X+2
    float b2, b3;   // yt col c-1, rows 2X+1, 2X+2
    float d2, d3;   // yt col c+1, rows 2X+1, 2X+2
    float e0, e1;   // yp col c,   rows 2X,   2X+1
};

template <int M>
__device__ __forceinline__ Pre& pick(Pre& A, Pre& B) {
    if constexpr (M == 0) return A;
    else return B;
}

// MFMA H-phase. rbuf: [8 rows][5 q][RPAD h2] (f16 col-major-packed: word w = cols 2w,2w+1).
// Per 16-col output tile: OUT[16r x 16c] = A[16 x 32] * B_toeplitz[32 x 16].
// A rows 0-7 = q_even image rows 0-7, rows 8-15 = q_odd. B[k][c] = g[k-c] (0<=k-c<=10).
// D mapping (m89): col = lane&15, row = (lane>>4)*4 + reg -> lane l / l+32 hold
// q_even / q_odd of the SAME 4 pixels; exchange via shfl_xor(32), 2 px SSIM per lane.
__device__ __forceinline__ void hphase_mfma(const h2 (*rb)[5][RPAD], int orow0,
                                            int tid, f16x8 bfrag, float& lsum) {
    const int lane = tid & 63;
    const int wv   = tid >> 6;
    const int colN = lane & 15;
    const int g4   = lane >> 4;          // k-group 0..3
    const int arow = lane & 15;          // A row 0..15
    const int r    = arow & 7;           // image row within phase
    const bool lo  = lane < 32;
    const int prow_base = 4 * (g4 & 1);
#pragma unroll
    for (int i = 0; i < 4; i++) {
        const int ct = wv * 4 + i;       // col tile 0..31
        const int c0 = ct << 4;
        const int wbase = (c0 >> 1) + (g4 << 2);
        const int q01 = (arow < 8) ? 0 : 1;
        const int q23 = (arow < 8) ? 2 : 3;
        f16x8 a0 = *(const f16x8*)&rb[r][q01][wbase];
        f16x8 a1 = *(const f16x8*)&rb[r][q23][wbase];
        f16x8 a2 = *(const f16x8*)&rb[r][4][wbase];
        if (arow >= 8) a2 = f16x8{0, 0, 0, 0, 0, 0, 0, 0};   // (q4, zero) pair
        f32x4 z = {0.f, 0.f, 0.f, 0.f};
        f32x4 d01 = __builtin_amdgcn_mfma_f32_16x16x32_f16(a0, bfrag, z, 0, 0, 0);
        f32x4 d23 = __builtin_amdgcn_mfma_f32_16x16x32_f16(a1, bfrag, z, 0, 0, 0);
        f32x4 d4  = __builtin_amdgcn_mfma_f32_16x16x32_f16(a2, bfrag, z, 0, 0, 0);
        // cross-half exchange: partner lane^32 has the other q of same pixels
        float x010 = __shfl_xor(d01[0], 32), x011 = __shfl_xor(d01[1], 32);
        float x012 = __shfl_xor(d01[2], 32), x013 = __shfl_xor(d01[3], 32);
        float x230 = __shfl_xor(d23[0], 32), x231 = __shfl_xor(d23[1], 32);
        float x232 = __shfl_xor(d23[2], 32), x233 = __shfl_xor(d23[3], 32);
        float x42  = __shfl_xor(d4[2],  32), x43  = __shfl_xor(d4[3],  32);
#pragma unroll
        for (int e = 0; e < 2; e++) {
            float mu1 = lo ? d01[e]              : (e ? x013 : x012);
            float mu2 = lo ? (e ? x011 : x010)   : d01[e + 2];
            float exx = lo ? d23[e]              : (e ? x233 : x232);
            float eyy = lo ? (e ? x231 : x230)   : d23[e + 2];
            float exy = lo ? d4[e]               : (e ? x43 : x42);
            const int rr = lo ? e : e + 2;
            const int grow = orow0 + prow_base + rr;
            const int gcol = c0 + colN;
            float m = (grow < OH && gcol < OW) ? 1.f : 0.f;
            float mu1s = mu1 * mu1, mu2s = mu2 * mu2, mu12 = mu1 * mu2;
            float s1 = exx - mu1s, s2 = eyy - mu2s, s12 = exy - mu12;
            float num = (2.f * mu12 + C1V) * (2.f * s12 + C2V);
            float den = (mu1s + mu2s + C1V) * (s1 + s2 + C2V);
            den = den * m + (1.f - m);        // masked: den=1 (no inf/NaN)
            lsum += m * num * __builtin_amdgcn_rcpf(den);
        }
    }
}

// one pair-step: input rows ir = O0+2S, ir+1 (depth-2 prefetch, in-place buffer)
// V-ring packed by OUTPUT-ROW PAIRS: acc2[p%6][q] = (out_{2p}, out_{2p+1}) in h2.
template <int S>
__device__ __forceinline__ void stepf(
    h2 (&acc2)[6][5], float& a0, float& a1, float& b1, float& d1,
    Pre& preA, Pre& preB,
    const float* __restrict__ ytb, const float* __restrict__ ypb,
    int O0, int c, int cm, int cp, bool cgt0, bool clt511,
    const h2 (&wA)[6], const h2 (&wB)[6], f16x8 bfrag,
    h2 (*rbuf)[5][RPAD], int tid, float& lsum) {
    Pre& cur = pick<S % 2>(preA, preB);
    // ---- consume cur first: edge-enhance rows ir, ir+1 ----
    float lf0 = cgt0 ? b1 : 0.f;
    float rt0 = clt511 ? d1 : 0.f;
    float lf1 = cgt0 ? cur.b2 : 0.f;
    float rt1 = clt511 ? cur.d2 : 0.f;
    float xr0 = a0 + cur.a2 + lf0 + rt0 - 4.f * a1;
    float xr1 = a1 + cur.a3 + lf1 + rt1 - 4.f * cur.a2;
    float pr0[5] = {xr0, cur.e0, xr0 * xr0, cur.e0 * cur.e0, xr0 * cur.e0};
    float pr1[5] = {xr1, cur.e1, xr1 * xr1, cur.e1 * cur.e1, xr1 * cur.e1};
    h2 bc0[5], bc1[5];
#pragma unroll
    for (int q = 0; q < 5; q++) {
        bc0[q] = pkrtz(pr0[q], pr0[q]);
        bc1[q] = pkrtz(pr1[q], pr1[q]);
    }
    a0 = cur.a2; a1 = cur.a3; b1 = cur.b3; d1 = cur.d3;
    // ---- issue loads for step S+2 into cur ----
    if constexpr (S + 2 <= LASTS) {
        const int r1 = min(O0 + 2 * S + 5, IH - 1);
        const int r2 = min(O0 + 2 * S + 6, IH - 1);
        const int rE = min(O0 + 2 * S + 4, IH - 1);
        const float* pr1p = ytb + (size_t)r1 * IW;
        const float* pr2p = ytb + (size_t)r2 * IW;
        const float* pe0p = ypb + (size_t)rE * IW;
        const float* pe1p = ypb + (size_t)r1 * IW;
        cur.a2 = pr1p[c];  cur.a3 = pr2p[c];
        cur.b2 = pr1p[cm]; cur.b3 = pr2p[cm];
        cur.d2 = pr1p[cp]; cur.d3 = pr2p[cp];
        cur.e0 = pe0p[c];  cur.e1 = pe1p[c];
    }
    // ---- packed V-ring: live output pairs p = S-5..S (clipped to [0,15]) ----
    constexpr int PLO = (S - 5 < 0) ? 0 : (S - 5);
    constexpr int PHI = (S > 15) ? 15 : S;
#pragma unroll
    for (int p = PLO; p <= PHI; ++p) {
        const int i = S - p;
        const int sl = p % 6;
#pragma unroll
        for (int q = 0; q < 5; q++) {
            if (i == 0) {
                acc2[sl][q] = wA[0] * bc0[q];
                acc2[sl][q] = wB[0] * bc1[q] + acc2[sl][q];
            } else {
                acc2[sl][q] = wA[i] * bc0[q] + acc2[sl][q];
                acc2[sl][q] = wB[i] * bc1[q] + acc2[sl][q];
            }
        }
    }
    // ---- emit pair p = S-5: transpose (row-pair pack) -> (col-pair pack) ----
    // even lane c: word (x_c, x_{c+1}) of row 2p; odd lane: row 2p+1 word (cols c-1,c)
    if constexpr (S >= 5) {
        constexpr int p = S - 5;
        constexpr int sl = p % 6;
        const int par = c & 1;
        const int row = ((2 * p) & 7) + par;
        int* lw = (int*)&rbuf[0][0][0];
        const int wb = (row * 5) * RPAD + (c >> 1);
#pragma unroll
        for (int q = 0; q < 5; q++) {
            int own = __builtin_bit_cast(int, acc2[sl][q]);
            int prt = __shfl_xor(own, 1);
            int we = (own & 0xffff) | (prt << 16);
            int wo = (int)(((unsigned)prt >> 16) | ((unsigned)own & 0xffff0000u));
            lw[wb + q * RPAD] = par ? wo : we;
        }
    }
    // ---- MFMA phase at S = 8,12,16,20 (lgkm-only barriers; vmcnt in flight) ----
    if constexpr (S >= 8 && ((S - 8) % 4) == 0) {
        asm volatile("s_waitcnt lgkmcnt(0)\n\ts_barrier" ::: "memory");
        hphase_mfma(rbuf, O0 + 8 * ((S - 8) / 4), tid, bfrag, lsum);
        if constexpr (S < LASTS)
            asm volatile("s_waitcnt lgkmcnt(0)\n\ts_barrier" ::: "memory");
    }
}

template <int S, typename... A>
__device__ __forceinline__ void run_steps(A&... a) {
    stepf<S>(a...);
    if constexpr (S < LASTS) run_steps<S + 1>(a...);
}

__global__ __launch_bounds__(512) void ssim_stream(const float* __restrict__ yt,
                                                   const float* __restrict__ yp,
                                                   float* __restrict__ partial) {
    __shared__ __align__(16) h2 rbuf[8][5][RPAD];   // 42,880 B
    __shared__ float lds_g[16];
    __shared__ float wred[8];

    const int tid = threadIdx.x;
    const int c = tid;
    const int strip = blockIdx.x;
    const int img = blockIdx.y;
    const int O0 = strip * ROWS;
    const size_t ib = (size_t)img * (IH * IW);
    const float* ytb = yt + ib;
    const float* ypb = yp + ib;

    const int cm = c > 0 ? c - 1 : 0;
    const int cp = c < (IW - 1) ? c + 1 : (IW - 1);
    const bool cgt0 = c > 0, clt511 = c < (IW - 1);

    // stage g table (idx 11..15 = 0) + zero pad words 256..267 of all 40 lines
    if (tid < 16) lds_g[tid] = (tid < 11) ? GFc[tid] : 0.f;
    for (int i = tid; i < 40 * 12; i += 512) {
        int line = i / 12, w = 256 + i % 12;
        (&rbuf[0][0][0])[line * RPAD + w] = h2{(_Float16)0.f, (_Float16)0.f};
    }
    __syncthreads();

    // B Toeplitz fragment (constant per lane): B[k][col] = g[k-col], k = 8*(l>>4)+j
    f16x8 bfrag;
    {
        const int lane = tid & 63;
#pragma unroll
        for (int j = 0; j < 8; j++) {
            int k = ((lane >> 4) << 3) + j;
            int idx = k - (lane & 15);
            idx = (idx < 0 || idx > 10) ? 15 : idx;
            bfrag[j] = (__fp16)lds_g[idx];
        }
    }

    // V-ring weights in SGPRs: wA[i]=(g[2i],g[2i-1]) g[-1]=0; wB[i]=(g[2i+1],g[2i]) g[11]=0
    h2 wA[6], wB[6];
    wA[0] = sgpr_h2(GFc[0], 0.f);
#pragma unroll
    for (int i = 1; i < 6; i++) wA[i] = sgpr_h2(GFc[2 * i], GFc[2 * i - 1]);
#pragma unroll
    for (int i = 0; i < 5; i++) wB[i] = sgpr_h2(GFc[2 * i + 1], GFc[2 * i]);
    wB[5] = sgpr_h2(0.f, GFc[10]);

    // prologue: carries + first TWO steps' loads
    float a0, a1, b1, d1;
    {
        const int rm1 = O0 > 0 ? O0 - 1 : 0;
        const float* pm1 = ytb + (size_t)rm1 * IW;
        const float* p0  = ytb + (size_t)O0 * IW;
        float a0v = pm1[c];
        a1 = p0[c]; b1 = p0[cm]; d1 = p0[cp];
        a0 = (O0 > 0) ? a0v : 0.f;
    }
    Pre preA, preB;
    auto fill = [&](Pre& dst, int X) {
        const int r1 = min(O0 + 2 * X + 1, IH - 1);
        const int r2 = min(O0 + 2 * X + 2, IH - 1);
        const int rE = min(O0 + 2 * X,     IH - 1);
        const float* pr1p = ytb + (size_t)r1 * IW;
        const float* pr2p = ytb + (size_t)r2 * IW;
        const float* pe0p = ypb + (size_t)rE * IW;
        const float* pe1p = ypb + (size_t)r1 * IW;
        dst.a2 = pr1p[c];  dst.a3 = pr2p[c];
        dst.b2 = pr1p[cm]; dst.b3 = pr2p[cm];
        dst.d2 = pr1p[cp]; dst.d3 = pr2p[cp];
        dst.e0 = pe0p[c];  dst.e1 = pe1p[c];
    };
    fill(preA, 0);
    fill(preB, 1);

    h2 acc2[6][5];
    float lsum = 0.f;

    run_steps<0>(acc2, a0, a1, b1, d1, preA, preB, ytb, ypb, O0,
                 c, cm, cp, cgt0, clt511, wA, wB, bfrag, rbuf, tid, lsum);

#pragma unroll
    for (int off = 32; off > 0; off >>= 1) lsum += __shfl_down(lsum, off);
    if ((tid & 63) == 0) wred[tid >> 6] = lsum;
    __syncthreads();
    if (tid == 0) {
        float s = 0.f;
#pragma unroll
        for (int w = 0; w < 8; w++) s += wred[w];
        partial[strip + NSTRIP * img] = s;
    }
}

__global__ __launch_bounds__(256) void ssim_final(const float* __restrict__ partial,
                                                  float* __restrict__ out) {
    __shared__ double wred[4];
    double s = 0.0;
    for (int i = threadIdx.x; i < NBLK; i += 256) s += (double)partial[i];
#pragma unroll
    for (int off = 32; off > 0; off >>= 1) s += __shfl_down(s, off);
    if ((threadIdx.x & 63) == 0) wred[threadIdx.x >> 6] = s;
    __syncthreads();
    if (threadIdx.x == 0) {
        double tot = wred[0] + wred[1] + wred[2] + wred[3];
        out[0] = (float)(1.0 - tot / (double)((long long)OH * OW * NIMG));
    }
}

extern "C" void kernel_launch(void* const* d_in, const int* in_sizes, int n_in,
                              void* d_out, int out_size, void* d_ws, size_t ws_size,
                              hipStream_t stream) {
    const float* yt = (const float*)d_in[0];
    const float* yp = (const float*)d_in[1];
    float* out = (float*)d_out;
    float* partial = (float*)d_ws;   // NBLK floats = 3 KB

    dim3 grid(NSTRIP, NIMG);
    hipLaunchKernelGGL(ssim_stream, grid, dim3(512), 0, stream, yt, yp, partial);
    hipLaunchKernelGGL(ssim_final, dim3(1), dim3(256), 0, stream, partial, out);
}